// Round 6
// baseline (461.109 us; speedup 1.0000x reference)
//
#include <hip/hip_runtime.h>

#define W 320

typedef __attribute__((ext_vector_type(8))) short   short8;
typedef __attribute__((ext_vector_type(4))) float   floatx4;

__device__ __forceinline__ unsigned int f2bf(float f) {
    // round-to-nearest-even fp32 -> bf16 (low 16 bits)
    unsigned int u = __float_as_uint(f);
    u += 0x7FFFu + ((u >> 16) & 1u);
    return u >> 16;
}

// Load one 16-row tile fragment set: per lane 8x floatx4 (row = col of tile,
// float elems quad*8 + q*32 .. +8). base already includes (bh*W+col)*128+quad*8.
#define LOAD8(buf, base, toff) do {                                         \
    const float* p_ = (base) + (size_t)(toff) * 2048;                       \
    _Pragma("unroll")                                                       \
    for (int q_ = 0; q_ < 4; ++q_) {                                        \
        buf[2*q_]   = *(const floatx4*)(p_ + q_*32);                        \
        buf[2*q_+1] = *(const floatx4*)(p_ + q_*32 + 4);                    \
    } } while (0)

// Convert 8x floatx4 raw -> 4x short8 bf16 fragments (RNE).
#define CONV8(dst, buf) do {                                                \
    _Pragma("unroll")                                                       \
    for (int q_ = 0; q_ < 4; ++q_) {                                        \
        short8 x_;                                                          \
        x_[0] = (short)f2bf(buf[2*q_].x);   x_[1] = (short)f2bf(buf[2*q_].y);   \
        x_[2] = (short)f2bf(buf[2*q_].z);   x_[3] = (short)f2bf(buf[2*q_].w);   \
        x_[4] = (short)f2bf(buf[2*q_+1].x); x_[5] = (short)f2bf(buf[2*q_+1].y); \
        x_[6] = (short)f2bf(buf[2*q_+1].z); x_[7] = (short)f2bf(buf[2*q_+1].w); \
        (dst)[q_] = x_;                                                     \
    } } while (0)

#define MFMA4(accv) do {                                                    \
    _Pragma("unroll")                                                       \
    for (int ks_ = 0; ks_ < 4; ++ks_)                                       \
        accv = __builtin_amdgcn_mfma_f32_16x16x32_bf16(Af[ks_], Bt[ks_],    \
                                                       accv, 0, 0, 0);     \
    } while (0)

// Max-MLP cost volume: one wave = one 16-j m-tile, 4 independent waves per
// block, no LDS, no barriers. Each wave bursts 24 KB of loads immediately,
// then rolls {load next R tile | convert + 4 MFMA} with 3 rotating buffers,
// so ~16-24 KB stays in flight for most of its ~2-3 us life. Short-lived
// waves are continuously replaced, keeping per-CU outstanding-load depth
// high (Little's law: the lever all prior variants lacked). R tiles re-read
// up to 5x at L2 (XCD-chunked swizzle keeps that on-die); HBM fetch ~unique.
__global__ __launch_bounds__(256, 3)
void cost_volume_kernel(const float* __restrict__ Lg,
                        const float* __restrict__ Rg,
                        float* __restrict__ out) {
    // 6400 blocks = 8 XCDs x 800; chunked bijective swizzle keeps one row's
    // 5 tile-groups (overlapping R windows) on one XCD's L2.
    const int lin  = blockIdx.x;
    const int work = (lin & 7) * 800 + (lin >> 3);
    const int bh   = work / 5;
    const int grp  = work - bh * 5;

    const int wave = threadIdx.x >> 6;
    const int t    = grp * 4 + wave;       // m-tile 0..19 (j = 16t .. 16t+15)
    const int lane = threadIdx.x & 63;
    const int col  = lane & 15;
    const int quad = lane >> 4;

    const float* Rb = Rg + ((size_t)bh * W + col) * 128 + quad * 8;
    const float* Lb = Lg + ((size_t)bh * W + col) * 128 + quad * 8;

    floatx4 bufA[8], bufB[8], bufC[8];
    short8  Af[4], Bt[4];

    // ---- issue burst: A(t), R(t-4), R(t-3) -- oldest-first for vmcnt ----
    LOAD8(bufC, Lb, t);
    if (t >= 4) LOAD8(bufA, Rb, t - 4);
    if (t >= 3) LOAD8(bufB, Rb, t - 3);

    CONV8(Af, bufC);                        // waits only on the A loads
    if (t >= 2) LOAD8(bufC, Rb, t - 2);

    floatx4 acc[5];
    #pragma unroll
    for (int v = 0; v < 5; ++v) {
        acc[v].x = 0.f; acc[v].y = 0.f; acc[v].z = 0.f; acc[v].w = 0.f;
    }

    // ---- rolling convert+MFMA; B-tile for acc[v] is tile t-4+v ----
    if (t >= 4) { CONV8(Bt, bufA); MFMA4(acc[0]); }
    if (t >= 1) LOAD8(bufA, Rb, t - 1);
    if (t >= 3) { CONV8(Bt, bufB); MFMA4(acc[1]); }
    LOAD8(bufB, Rb, t);
    if (t >= 2) { CONV8(Bt, bufC); MFMA4(acc[2]); }
    if (t >= 1) { CONV8(Bt, bufA); MFMA4(acc[3]); }
    CONV8(Bt, bufB); MFMA4(acc[4]);

    // ---- stores: j = 16t + m, m = quad*4+r; k-row = 16(t-4+v)+col;
    // i = j-k = 64-16v+m-col. v=1..3 always in [0,64); v=0 needs m<col,
    // v=4 needs m>=col. Skipped tiles (t-4+v<0) store required zeros.
    float* orow = out + ((size_t)bh * W + (size_t)t * 16) * 64;
    #pragma unroll
    for (int v = 0; v < 5; ++v) {
        #pragma unroll
        for (int r = 0; r < 4; ++r) {
            const int m = quad * 4 + r;
            const int i = 64 - 16 * v + m - col;
            const bool ok = (v == 0) ? (m < col) : (v == 4) ? (m >= col) : true;
            if (ok) orow[(size_t)m * 64 + i] = acc[v][r] * 0.0078125f;   // /128
        }
    }
}

extern "C" void kernel_launch(void* const* d_in, const int* in_sizes, int n_in,
                              void* d_out, int out_size, void* d_ws, size_t ws_size,
                              hipStream_t stream) {
    const float* L = (const float*)d_in[0];
    const float* R = (const float*)d_in[1];
    float* out = (float*)d_out;
    dim3 grid(8 * 160 * 5);   // 6400 blocks x 256 threads; wave = m-tile
    cost_volume_kernel<<<grid, 256, 0, stream>>>(L, R, out);
}